// Round 4
// baseline (782.219 us; speedup 1.0000x reference)
//
#include <hip/hip_runtime.h>
#include <math.h>

// DeeperGCN on MI355X. N=50000, E=625000, D=128, L=7.
// CSR-by-dst build per call with combined-bond-index records {src, cidx};
// comb[512][128] table precomputed (L2-resident); single-pass softmax
// aggregation with NO max subtraction (logits structurally bounded <~13);
// fp32 register-tiled GEMM with fused LayerNorm(+ReLU) epilogue.

constexpr int D = 128;
constexpr int NA = 9;   // atom feats
constexpr int NB = 3;   // bond feats

// ------------------------- CSR build -------------------------

__global__ void k_hist(const int* __restrict__ dst, int* __restrict__ deg, int E) {
    int e = blockIdx.x * 256 + threadIdx.x;
    if (e < E) atomicAdd(&deg[dst[e]], 1);
}

__global__ void k_scan_a(const int* __restrict__ deg, int* __restrict__ offs,
                         int* __restrict__ bsum, int N) {
    __shared__ int s[256];
    int i = blockIdx.x * 256 + threadIdx.x;
    int v = (i < N) ? deg[i] : 0;
    s[threadIdx.x] = v;
    __syncthreads();
    for (int d = 1; d < 256; d <<= 1) {
        int add = (threadIdx.x >= d) ? s[threadIdx.x - d] : 0;
        __syncthreads();
        s[threadIdx.x] += add;
        __syncthreads();
    }
    if (i < N) offs[i + 1] = s[threadIdx.x];
    if (threadIdx.x == 255) bsum[blockIdx.x] = s[255];
    if (i == 0) offs[0] = 0;
}

// nb must be <= 256 (N=50000 -> nb=196)
__global__ void k_scan_b(const int* __restrict__ bsum, int* __restrict__ bexc, int nb) {
    __shared__ int s[256];
    int t = threadIdx.x;
    int v = (t < nb) ? bsum[t] : 0;
    s[t] = v;
    __syncthreads();
    for (int d = 1; d < 256; d <<= 1) {
        int add = (t >= d) ? s[t - d] : 0;
        __syncthreads();
        s[t] += add;
        __syncthreads();
    }
    if (t < nb) bexc[t] = s[t] - v;  // exclusive block prefix
}

__global__ void k_scan_c(int* __restrict__ offs, const int* __restrict__ bexc, int N) {
    int i = blockIdx.x * 256 + threadIdx.x;
    if (i < N) offs[i + 1] += bexc[blockIdx.x];
}

__global__ void k_fill(const int* __restrict__ src, const int* __restrict__ dst,
                       const int* __restrict__ attr, const int* __restrict__ offs,
                       int* __restrict__ cur, int2* __restrict__ recs, int E) {
    int e = blockIdx.x * 256 + threadIdx.x;
    if (e >= E) return;
    int d = dst[e];
    int pos = offs[d] + atomicAdd(&cur[d], 1);
    int cidx = attr[e * 3] * 64 + attr[e * 3 + 1] * 8 + attr[e * 3 + 2];
    recs[pos] = make_int2(src[e], cidx);
}

// comb[c][d] = b0[c>>6][d] + b1[(c>>3)&7][d] + b2[c&7][d]   (512 x 128)
__global__ void k_comb(const float* __restrict__ bemb, float* __restrict__ comb) {
    int gid = blockIdx.x * 256 + threadIdx.x;  // 512*32 float4s
    int c = gid >> 5, q = gid & 31;
    int a0 = c >> 6, a1 = (c >> 3) & 7, a2 = c & 7;
    float4 v0 = *(const float4*)(bemb + (a0)*D + q * 4);
    float4 v1 = *(const float4*)(bemb + (8 + a1) * D + q * 4);
    float4 v2 = *(const float4*)(bemb + (16 + a2) * D + q * 4);
    float4 r;
    r.x = v0.x + v1.x + v2.x;
    r.y = v0.y + v1.y + v2.y;
    r.z = v0.z + v1.z + v2.z;
    r.w = v0.w + v1.w + v2.w;
    *(float4*)(comb + c * D + q * 4) = r;
}

// ------------------------- Atom encoder -------------------------
// wave per node; lane holds d = 2*lane, 2*lane+1

__global__ void k_atom(const int* __restrict__ x, const float* __restrict__ aemb,
                       float* __restrict__ h, int N) {
    int wid = (blockIdx.x * blockDim.x + threadIdx.x) >> 6;
    int lane = threadIdx.x & 63;
    if (wid >= N) return;
    const int* xr = x + wid * NA;
    float ax = 0.f, ay = 0.f;
#pragma unroll
    for (int f = 0; f < NA; ++f) {
        int v = xr[f];  // wave-uniform broadcast
        const float2 e = *(const float2*)(aemb + (f * 64 + v) * D + 2 * lane);
        ax += e.x; ay += e.y;
    }
    *(float2*)(h + wid * D + 2 * lane) = make_float2(ax, ay);
}

// ------------------------- Aggregation (direct-exp softmax) ----------------
// wave per node; t[n] = hconv[n] + m[n]. No max subtraction: logits are
// bounded (LN output <= sqrt(127), comb small) so exp2 never overflows.
// Edge metadata scalarized (SGPR bases -> zero VALU addressing); A/B
// double-group pipeline (4 edges/group), -inf-masked dummy slots.

__global__ __launch_bounds__(256) void k_agg(const float* __restrict__ hconv,
                      const int2* __restrict__ recs,
                      const int* __restrict__ offs, const float* __restrict__ comb,
                      float* __restrict__ t, int N) {
    int wid = (blockIdx.x * blockDim.x + threadIdx.x) >> 6;
    int lane = threadIdx.x & 63;
    if (wid >= N) return;
    int su = __builtin_amdgcn_readfirstlane(offs[wid]);
    int eu = __builtin_amdgcn_readfirstlane(offs[wid + 1]);
    int dl = 2 * lane;
    float2 hme = *(const float2*)(hconv + wid * D + dl);
    if (su >= eu) {  // empty segment: m = 0
        *(float2*)(t + wid * D + dl) = hme;
        return;
    }
    constexpr float L2E = 1.4426950408889634f;
    float Sx = 0.f, Sy = 0.f, Wx = 0.f, Wy = 0.f;
    int last = eu - 1;

    const float2* hrow = (const float2*)hconv + lane;  // row r at hrow[r*64]
    const float2* crow = (const float2*)comb + lane;

    float2 ha[4], ca[4], hb[4], cb[4];

    auto loadg = [&](int gb, float2* hs, float2* cs) {
#pragma unroll
        for (int i = 0; i < 4; ++i) {
            int idx = gb + i; idx = (idx < last) ? idx : last;
            int2 rr = recs[idx];
            int sj = __builtin_amdgcn_readfirstlane(rr.x);
            int cj = __builtin_amdgcn_readfirstlane(rr.y);
            hs[i] = hrow[sj * 64];
            cs[i] = crow[cj * 64];
        }
    };
    auto compg = [&](int gb, const float2* hs, const float2* cs) {
        float px[4], py[4], vx[4], vy[4];
#pragma unroll
        for (int i = 0; i < 4; ++i) {
            vx[i] = fmaxf(hs[i].x + cs[i].x, 0.f) + 1e-7f;
            vy[i] = fmaxf(hs[i].y + cs[i].y, 0.f) + 1e-7f;
            bool valid = (gb + i) < eu;  // wave-uniform
            float uxv = valid ? vx[i] * L2E : -INFINITY;
            float uyv = valid ? vy[i] * L2E : -INFINITY;
            px[i] = __builtin_amdgcn_exp2f(uxv);
            py[i] = __builtin_amdgcn_exp2f(uyv);
        }
        Sx += (px[0] + px[1]) + (px[2] + px[3]);
        Sy += (py[0] + py[1]) + (py[2] + py[3]);
        Wx += fmaf(px[0], vx[0], px[1] * vx[1]) + fmaf(px[2], vx[2], px[3] * vx[3]);
        Wy += fmaf(py[0], vy[0], py[1] * vy[1]) + fmaf(py[2], vy[2], py[3] * vy[3]);
    };

    loadg(su, ha, ca);
    loadg(su + 4, hb, cb);
    for (int e = su; e < eu; e += 8) {
        compg(e, ha, ca);
        loadg(e + 8, ha, ca);      // prefetch for next iteration's A
        compg(e + 4, hb, cb);
        loadg(e + 12, hb, cb);     // prefetch for next iteration's B
    }
    float mx = Wx / (Sx + 1e-16f);
    float my = Wy / (Sy + 1e-16f);
    *(float2*)(t + wid * D + dl) = make_float2(hme.x + mx, hme.y + my);
}

// ------------------------- GEMM + fused LN(+ReLU) -------------------------
// outh = A @ W + b (+ res); hc = LN(outh)*g+beta [ReLU opt].
// 64-node tile, 256 threads, 4x8 micro-tile. Row lives across 16 lanes of
// one wave -> shfl_xor reduction for LN mean/var.

template <int RELU>
__global__ __launch_bounds__(256) void k_gemm(const float* __restrict__ A,
                                              const float* __restrict__ Wl,
                                              const float* __restrict__ bl,
                                              const float* __restrict__ res,
                                              float* __restrict__ outh,
                                              const float* __restrict__ g,
                                              const float* __restrict__ bta,
                                              float* __restrict__ hc,
                                              int N, int useRes) {
    __shared__ float As[64 * 36];   // [m][k] padded stride 36
    __shared__ float Bs[32 * 128];  // [k][j]
    int tid = threadIdx.x;
    int tx = tid & 15;   // j-group: dims tx*8 .. tx*8+7
    int ty = tid >> 4;   // m-group: rows ty + 16*i, i=0..3
    int m0 = blockIdx.x * 64;

    float acc[4][8];
#pragma unroll
    for (int i = 0; i < 4; ++i)
#pragma unroll
        for (int j = 0; j < 8; ++j) acc[i][j] = 0.f;

    for (int kk0 = 0; kk0 < 128; kk0 += 32) {
#pragma unroll
        for (int it = 0; it < 2; ++it) {  // stage A chunk: 64x32
            int lin = it * 256 + tid;
            int node = lin >> 3, kq = lin & 7;
            int gm = m0 + node;
            float4 va = (gm < N) ? *(const float4*)(A + gm * 128 + kk0 + kq * 4)
                                 : make_float4(0.f, 0.f, 0.f, 0.f);
            *(float4*)(As + node * 36 + kq * 4) = va;
        }
#pragma unroll
        for (int it = 0; it < 4; ++it) {  // stage B chunk: 32x128
            int lin = it * 256 + tid;
            int k = lin >> 5, jq = lin & 31;
            *(float4*)(Bs + k * 128 + jq * 4) = *(const float4*)(Wl + (kk0 + k) * 128 + jq * 4);
        }
        __syncthreads();
#pragma unroll
        for (int kk = 0; kk < 32; ++kk) {
            float4 b0 = *(const float4*)(Bs + kk * 128 + tx * 8);
            float4 b1 = *(const float4*)(Bs + kk * 128 + tx * 8 + 4);
            float av[4];
#pragma unroll
            for (int i = 0; i < 4; ++i) av[i] = As[(ty + 16 * i) * 36 + kk];
#pragma unroll
            for (int i = 0; i < 4; ++i) {
                float a = av[i];
                acc[i][0] = fmaf(a, b0.x, acc[i][0]);
                acc[i][1] = fmaf(a, b0.y, acc[i][1]);
                acc[i][2] = fmaf(a, b0.z, acc[i][2]);
                acc[i][3] = fmaf(a, b0.w, acc[i][3]);
                acc[i][4] = fmaf(a, b1.x, acc[i][4]);
                acc[i][5] = fmaf(a, b1.y, acc[i][5]);
                acc[i][6] = fmaf(a, b1.z, acc[i][6]);
                acc[i][7] = fmaf(a, b1.w, acc[i][7]);
            }
        }
        __syncthreads();
    }

    float4 bb0 = *(const float4*)(bl + tx * 8);
    float4 bb1 = *(const float4*)(bl + tx * 8 + 4);
    float4 gg0 = *(const float4*)(g + tx * 8);
    float4 gg1 = *(const float4*)(g + tx * 8 + 4);
    float4 bt0 = *(const float4*)(bta + tx * 8);
    float4 bt1 = *(const float4*)(bta + tx * 8 + 4);
#pragma unroll
    for (int i = 0; i < 4; ++i) {
        int gm = m0 + ty + 16 * i;
        bool ok = gm < N;
        float o[8];
#pragma unroll
        for (int j = 0; j < 8; ++j) o[j] = acc[i][j];
        o[0] += bb0.x; o[1] += bb0.y; o[2] += bb0.z; o[3] += bb0.w;
        o[4] += bb1.x; o[5] += bb1.y; o[6] += bb1.z; o[7] += bb1.w;
        if (useRes && ok) {
            float4 r0 = *(const float4*)(res + gm * 128 + tx * 8);
            float4 r1 = *(const float4*)(res + gm * 128 + tx * 8 + 4);
            o[0] += r0.x; o[1] += r0.y; o[2] += r0.z; o[3] += r0.w;
            o[4] += r1.x; o[5] += r1.y; o[6] += r1.z; o[7] += r1.w;
        }
        if (ok) {
            *(float4*)(outh + gm * 128 + tx * 8) = make_float4(o[0], o[1], o[2], o[3]);
            *(float4*)(outh + gm * 128 + tx * 8 + 4) = make_float4(o[4], o[5], o[6], o[7]);
        }
        // LN across the 16-lane tx group (same wave)
        float s = 0.f, ss = 0.f;
#pragma unroll
        for (int j = 0; j < 8; ++j) { s += o[j]; ss += o[j] * o[j]; }
#pragma unroll
        for (int off = 1; off < 16; off <<= 1) {
            s += __shfl_xor(s, off, 64);
            ss += __shfl_xor(ss, off, 64);
        }
        float mu = s * (1.f / 128.f);
        float var = ss * (1.f / 128.f) - mu * mu;
        float rs = rsqrtf(var + 1e-5f);
        float l[8];
        l[0] = (o[0] - mu) * rs * gg0.x + bt0.x;
        l[1] = (o[1] - mu) * rs * gg0.y + bt0.y;
        l[2] = (o[2] - mu) * rs * gg0.z + bt0.z;
        l[3] = (o[3] - mu) * rs * gg0.w + bt0.w;
        l[4] = (o[4] - mu) * rs * gg1.x + bt1.x;
        l[5] = (o[5] - mu) * rs * gg1.y + bt1.y;
        l[6] = (o[6] - mu) * rs * gg1.z + bt1.z;
        l[7] = (o[7] - mu) * rs * gg1.w + bt1.w;
        if (RELU) {
#pragma unroll
            for (int j = 0; j < 8; ++j) l[j] = fmaxf(l[j], 0.f);
        }
        if (ok) {
            *(float4*)(hc + gm * 128 + tx * 8) = make_float4(l[0], l[1], l[2], l[3]);
            *(float4*)(hc + gm * 128 + tx * 8 + 4) = make_float4(l[4], l[5], l[6], l[7]);
        }
    }
}

// ------------------------- Launch -------------------------

extern "C" void kernel_launch(void* const* d_in, const int* in_sizes, int n_in,
                              void* d_out, int out_size, void* d_ws, size_t ws_size,
                              hipStream_t stream) {
    const int*   x    = (const int*)d_in[0];
    const int*   ei   = (const int*)d_in[1];
    const int*   attr = (const int*)d_in[2];
    const float* aemb = (const float*)d_in[3];
    const float* bemb = (const float*)d_in[4];
    const float* Wf   = (const float*)d_in[5];
    const float* bf   = (const float*)d_in[6];
    const float* gam  = (const float*)d_in[7];
    const float* bet  = (const float*)d_in[8];
    float* out = (float*)d_out;

    const int N = in_sizes[0] / NA;        // 50000
    const int E = in_sizes[1] / 2;         // 625000
    const int L = in_sizes[5] / (D * D);   // 7

    char* ws = (char*)d_ws;
    size_t o = 0;
    auto carve = [&](size_t bytes) -> void* {
        void* p = (void*)(ws + o);
        o += (bytes + 255) & ~(size_t)255;
        return p;
    };
    float* h     = (float*)carve((size_t)N * D * 4);
    float* hconv = (float*)carve((size_t)N * D * 4);
    float* t     = (float*)carve((size_t)N * D * 4);
    int2*  recs  = (int2*)carve((size_t)E * 8);
    float* comb  = (float*)carve(512 * D * 4);
    int*   deg   = (int*)carve((size_t)N * 4);
    int*   cur   = (int*)carve((size_t)N * 4);
    int*   offs  = (int*)carve((size_t)(N + 1) * 4);
    int*   bsum  = (int*)carve(4096);
    int*   bexc  = (int*)carve(4096);

    const int* src = ei;
    const int* dst = ei + E;

    hipMemsetAsync(deg, 0, (size_t)N * 4, stream);
    hipMemsetAsync(cur, 0, (size_t)N * 4, stream);

    int ebl = (E + 255) / 256;
    int nbl = (N + 255) / 256;  // 196 (<=256 required by k_scan_b)
    k_comb<<<64, 256, 0, stream>>>(bemb, comb);
    k_hist<<<ebl, 256, 0, stream>>>(dst, deg, E);
    k_scan_a<<<nbl, 256, 0, stream>>>(deg, offs, bsum, N);
    k_scan_b<<<1, 256, 0, stream>>>(bsum, bexc, nbl);
    k_scan_c<<<nbl, 256, 0, stream>>>(offs, bexc, N);
    k_fill<<<ebl, 256, 0, stream>>>(src, dst, attr, offs, cur, recs, E);

    int wbl = (N * 64 + 255) / 256;  // wave per node, 4 waves/block
    k_atom<<<wbl, 256, 0, stream>>>(x, aemb, h, N);

    int gbl = (N + 63) / 64;   // k_gemm: 64-node tiles
    for (int l = 0; l < L; ++l) {
        const float* hc_in = (l == 0) ? h : hconv;
        k_agg<<<wbl, 256, 0, stream>>>(hc_in, recs, offs, comb, t, N);
        // gemm_l writes h_l and fused LN(gamma[l]) -> hconv (ReLU) or out (final)
        if (l == L - 1) {
            k_gemm<0><<<gbl, 256, 0, stream>>>(t, Wf + l * D * D, bf + l * D, h, h,
                                               gam + l * D, bet + l * D, out, N, l > 0 ? 1 : 0);
        } else {
            k_gemm<1><<<gbl, 256, 0, stream>>>(t, Wf + l * D * D, bf + l * D, h, h,
                                               gam + l * D, bet + l * D, hconv, N, l > 0 ? 1 : 0);
        }
    }
}

// Round 5
// 696.221 us; speedup vs baseline: 1.1235x; 1.1235x over previous
//
#include <hip/hip_runtime.h>
#include <hip/hip_fp16.h>
#include <math.h>

// DeeperGCN on MI355X. N=50000, E=625000, D=128, L=7.
// CSR-by-dst build; fp16 gather tables (h16, comb16) to halve L1 gather
// bytes in the softmax aggregation; direct-exp online softmax (no max:
// logits structurally bounded); fp32 VALU GEMM (128x128 tile, 8x8 micro,
// transposed-A LDS, conflict-free reads) with fused bias/res/LN(+ReLU)
// epilogue that also emits the next layer's fp16 gather table.

constexpr int D = 128;
constexpr int NA = 9;   // atom feats
constexpr int NB = 3;   // bond feats

// ------------------------- CSR build -------------------------

__global__ void k_hist(const int* __restrict__ dst, int* __restrict__ deg, int E) {
    int e = blockIdx.x * 256 + threadIdx.x;
    if (e < E) atomicAdd(&deg[dst[e]], 1);
}

__global__ void k_scan_a(const int* __restrict__ deg, int* __restrict__ offs,
                         int* __restrict__ bsum, int N) {
    __shared__ int s[256];
    int i = blockIdx.x * 256 + threadIdx.x;
    int v = (i < N) ? deg[i] : 0;
    s[threadIdx.x] = v;
    __syncthreads();
    for (int d = 1; d < 256; d <<= 1) {
        int add = (threadIdx.x >= d) ? s[threadIdx.x - d] : 0;
        __syncthreads();
        s[threadIdx.x] += add;
        __syncthreads();
    }
    if (i < N) offs[i + 1] = s[threadIdx.x];
    if (threadIdx.x == 255) bsum[blockIdx.x] = s[255];
    if (i == 0) offs[0] = 0;
}

// nb must be <= 256 (N=50000 -> nb=196)
__global__ void k_scan_b(const int* __restrict__ bsum, int* __restrict__ bexc, int nb) {
    __shared__ int s[256];
    int t = threadIdx.x;
    int v = (t < nb) ? bsum[t] : 0;
    s[t] = v;
    __syncthreads();
    for (int d = 1; d < 256; d <<= 1) {
        int add = (t >= d) ? s[t - d] : 0;
        __syncthreads();
        s[t] += add;
        __syncthreads();
    }
    if (t < nb) bexc[t] = s[t] - v;  // exclusive block prefix
}

__global__ void k_scan_c(int* __restrict__ offs, const int* __restrict__ bexc, int N) {
    int i = blockIdx.x * 256 + threadIdx.x;
    if (i < N) offs[i + 1] += bexc[blockIdx.x];
}

__global__ void k_fill(const int* __restrict__ src, const int* __restrict__ dst,
                       const int* __restrict__ attr, const int* __restrict__ offs,
                       int* __restrict__ cur, int2* __restrict__ recs, int E) {
    int e = blockIdx.x * 256 + threadIdx.x;
    if (e >= E) return;
    int d = dst[e];
    int pos = offs[d] + atomicAdd(&cur[d], 1);
    int cidx = attr[e * 3] * 64 + attr[e * 3 + 1] * 8 + attr[e * 3 + 2];
    recs[pos] = make_int2(src[e], cidx);
}

// comb16[c][d] = fp16(b0[c>>6][d] + b1[(c>>3)&7][d] + b2[c&7][d])   (512 x 128)
__global__ void k_comb(const float* __restrict__ bemb, __half* __restrict__ comb16) {
    int gid = blockIdx.x * 256 + threadIdx.x;  // 512*32 float4s
    int c = gid >> 5, q = gid & 31;
    int a0 = c >> 6, a1 = (c >> 3) & 7, a2 = c & 7;
    float4 v0 = *(const float4*)(bemb + (a0)*D + q * 4);
    float4 v1 = *(const float4*)(bemb + (8 + a1) * D + q * 4);
    float4 v2 = *(const float4*)(bemb + (16 + a2) * D + q * 4);
    __half2* c2 = (__half2*)comb16;
    c2[c * 64 + q * 2]     = __floats2half2_rn(v0.x + v1.x + v2.x, v0.y + v1.y + v2.y);
    c2[c * 64 + q * 2 + 1] = __floats2half2_rn(v0.z + v1.z + v2.z, v0.w + v1.w + v2.w);
}

// ------------------------- Atom encoder -------------------------
// wave per node; lane holds d = 2*lane, 2*lane+1. Emits fp16 gather table.

__global__ void k_atom(const int* __restrict__ x, const float* __restrict__ aemb,
                       __half* __restrict__ h16, int N) {
    int wid = (blockIdx.x * blockDim.x + threadIdx.x) >> 6;
    int lane = threadIdx.x & 63;
    if (wid >= N) return;
    const int* xr = x + wid * NA;
    float ax = 0.f, ay = 0.f;
#pragma unroll
    for (int f = 0; f < NA; ++f) {
        int v = xr[f];  // wave-uniform broadcast
        const float2 e = *(const float2*)(aemb + (f * 64 + v) * D + 2 * lane);
        ax += e.x; ay += e.y;
    }
    ((__half2*)h16)[wid * 64 + lane] = __floats2half2_rn(ax, ay);
}

// ------------------------- Aggregation (direct-exp softmax, fp16 gathers) --
// wave per node; t[n] = h16[n] + m[n]. Logits bounded (<~13) so exp2 never
// overflows -> no running max. Edge metadata scalarized; A/B double-group
// pipeline (4 edges/group), -inf-masked dummy slots.

__global__ __launch_bounds__(256) void k_agg(const __half* __restrict__ h16,
                      const int2* __restrict__ recs,
                      const int* __restrict__ offs, const __half* __restrict__ comb16,
                      float* __restrict__ t, int N) {
    int wid = (blockIdx.x * blockDim.x + threadIdx.x) >> 6;
    int lane = threadIdx.x & 63;
    if (wid >= N) return;
    int su = __builtin_amdgcn_readfirstlane(offs[wid]);
    int eu = __builtin_amdgcn_readfirstlane(offs[wid + 1]);
    int dl = 2 * lane;
    __half2 hm2 = ((const __half2*)h16)[wid * 64 + lane];
    float2 hme = make_float2(__low2float(hm2), __high2float(hm2));
    if (su >= eu) {  // empty segment: m = 0
        *(float2*)(t + wid * D + dl) = hme;
        return;
    }
    constexpr float L2E = 1.4426950408889634f;
    float Sx = 0.f, Sy = 0.f, Wx = 0.f, Wy = 0.f;
    int last = eu - 1;

    const __half2* hrow = (const __half2*)h16 + lane;    // row r at hrow[r*64]
    const __half2* crow = (const __half2*)comb16 + lane;

    __half2 ha[4], ca[4], hb[4], cb[4];

    auto loadg = [&](int gb, __half2* hs, __half2* cs) {
#pragma unroll
        for (int i = 0; i < 4; ++i) {
            int idx = gb + i; idx = (idx < last) ? idx : last;
            int2 rr = recs[idx];
            int sj = __builtin_amdgcn_readfirstlane(rr.x);
            int cj = __builtin_amdgcn_readfirstlane(rr.y);
            hs[i] = hrow[sj * 64];
            cs[i] = crow[cj * 64];
        }
    };
    auto compg = [&](int gb, const __half2* hs, const __half2* cs) {
        float px[4], py[4], vx[4], vy[4];
#pragma unroll
        for (int i = 0; i < 4; ++i) {
            float hx = __low2float(hs[i]), hy = __high2float(hs[i]);
            float cx = __low2float(cs[i]), cy = __high2float(cs[i]);
            vx[i] = fmaxf(hx + cx, 0.f) + 1e-7f;
            vy[i] = fmaxf(hy + cy, 0.f) + 1e-7f;
            bool valid = (gb + i) < eu;  // wave-uniform
            float uxv = valid ? vx[i] * L2E : -INFINITY;
            float uyv = valid ? vy[i] * L2E : -INFINITY;
            px[i] = __builtin_amdgcn_exp2f(uxv);
            py[i] = __builtin_amdgcn_exp2f(uyv);
        }
        Sx += (px[0] + px[1]) + (px[2] + px[3]);
        Sy += (py[0] + py[1]) + (py[2] + py[3]);
        Wx += fmaf(px[0], vx[0], px[1] * vx[1]) + fmaf(px[2], vx[2], px[3] * vx[3]);
        Wy += fmaf(py[0], vy[0], py[1] * vy[1]) + fmaf(py[2], vy[2], py[3] * vy[3]);
    };

    loadg(su, ha, ca);
    loadg(su + 4, hb, cb);
    for (int e = su; e < eu; e += 8) {
        compg(e, ha, ca);
        loadg(e + 8, ha, ca);      // prefetch for next iteration's A
        compg(e + 4, hb, cb);
        loadg(e + 12, hb, cb);     // prefetch for next iteration's B
    }
    float mx = Wx / (Sx + 1e-16f);
    float my = Wy / (Sy + 1e-16f);
    *(float2*)(t + wid * D + dl) = make_float2(hme.x + mx, hme.y + my);
}

// ------------------------- GEMM + fused LN(+ReLU) -------------------------
// h_out = A @ W + b (+ res). MODE 0: write h_out fp32 + h16 = fp16(relu(LN)).
// MODE 1 (last layer): write out = LN(h_out) fp32 only.
// 128x128 tile, 256 threads, 8x8 micro-tile. A staged transposed As[k][m]
// (stride 132 -> conflict-free b128 fragment reads); B read as b64 pairs at
// j = tx*2 + 32*jj (all 32 banks hit exactly once -> conflict-free).

template <int MODE>
__global__ __launch_bounds__(256) void k_gemm(const float* __restrict__ A,
                                              const float* __restrict__ Wl,
                                              const float* __restrict__ bl,
                                              const float* __restrict__ res,
                                              float* __restrict__ outh,
                                              const float* __restrict__ g,
                                              const float* __restrict__ bta,
                                              __half* __restrict__ h16,
                                              float* __restrict__ out,
                                              int N, int useRes) {
    __shared__ float As[32 * 132];  // [k][m], m-contiguous, stride 132
    __shared__ float Bs[32 * 128];  // [k][j]
    int tid = threadIdx.x;
    int tx = tid & 15;   // j lanes: j = tx*2 + 32*jj + s
    int ty = tid >> 4;   // m rows: ty*8 + i, i=0..7
    int m0 = blockIdx.x * 128;

    float acc[8][8];
#pragma unroll
    for (int i = 0; i < 8; ++i)
#pragma unroll
        for (int j = 0; j < 8; ++j) acc[i][j] = 0.f;

    for (int kk0 = 0; kk0 < 128; kk0 += 32) {
#pragma unroll
        for (int it = 0; it < 4; ++it) {  // stage A chunk 128x32, transposed
            int lin = it * 256 + tid;
            int node = lin >> 3, kq = lin & 7;
            int gm = m0 + node;
            float4 va = (gm < N) ? *(const float4*)(A + gm * 128 + kk0 + kq * 4)
                                 : make_float4(0.f, 0.f, 0.f, 0.f);
            As[(kq * 4 + 0) * 132 + node] = va.x;
            As[(kq * 4 + 1) * 132 + node] = va.y;
            As[(kq * 4 + 2) * 132 + node] = va.z;
            As[(kq * 4 + 3) * 132 + node] = va.w;
        }
#pragma unroll
        for (int it = 0; it < 4; ++it) {  // stage B chunk 32x128
            int lin = it * 256 + tid;
            int k = lin >> 5, jq = lin & 31;
            *(float4*)(Bs + k * 128 + jq * 4) = *(const float4*)(Wl + (kk0 + k) * 128 + jq * 4);
        }
        __syncthreads();
#pragma unroll
        for (int kk = 0; kk < 32; ++kk) {
            float4 a_lo = *(const float4*)(As + kk * 132 + ty * 8);
            float4 a_hi = *(const float4*)(As + kk * 132 + ty * 8 + 4);
            float2 bv[4];
#pragma unroll
            for (int jj = 0; jj < 4; ++jj)
                bv[jj] = *(const float2*)(Bs + kk * 128 + tx * 2 + 32 * jj);
            float am[8] = {a_lo.x, a_lo.y, a_lo.z, a_lo.w,
                           a_hi.x, a_hi.y, a_hi.z, a_hi.w};
#pragma unroll
            for (int i = 0; i < 8; ++i)
#pragma unroll
                for (int jj = 0; jj < 4; ++jj) {
                    acc[i][2 * jj]     = fmaf(am[i], bv[jj].x, acc[i][2 * jj]);
                    acc[i][2 * jj + 1] = fmaf(am[i], bv[jj].y, acc[i][2 * jj + 1]);
                }
        }
        __syncthreads();
    }

    // epilogue: j(jj,s) = 32*jj + tx*2 + s
    float2 bb[4], gg[4], bt[4];
#pragma unroll
    for (int jj = 0; jj < 4; ++jj) {
        bb[jj] = *(const float2*)(bl + tx * 2 + 32 * jj);
        gg[jj] = *(const float2*)(g + tx * 2 + 32 * jj);
        bt[jj] = *(const float2*)(bta + tx * 2 + 32 * jj);
    }
#pragma unroll
    for (int i = 0; i < 8; ++i) {
        int gm = m0 + ty * 8 + i;
        bool ok = gm < N;
        float o[8];
#pragma unroll
        for (int jj = 0; jj < 4; ++jj) {
            o[2 * jj]     = acc[i][2 * jj] + bb[jj].x;
            o[2 * jj + 1] = acc[i][2 * jj + 1] + bb[jj].y;
        }
        if (useRes && ok) {
#pragma unroll
            for (int jj = 0; jj < 4; ++jj) {
                float2 rr = *(const float2*)(res + gm * 128 + tx * 2 + 32 * jj);
                o[2 * jj] += rr.x;
                o[2 * jj + 1] += rr.y;
            }
        }
        if (MODE == 0 && ok) {
#pragma unroll
            for (int jj = 0; jj < 4; ++jj)
                *(float2*)(outh + gm * 128 + tx * 2 + 32 * jj) =
                    make_float2(o[2 * jj], o[2 * jj + 1]);
        }
        // LN across the 16-lane tx group (same wave)
        float s = 0.f, ss = 0.f;
#pragma unroll
        for (int j = 0; j < 8; ++j) { s += o[j]; ss += o[j] * o[j]; }
#pragma unroll
        for (int off = 1; off < 16; off <<= 1) {
            s += __shfl_xor(s, off, 64);
            ss += __shfl_xor(ss, off, 64);
        }
        float mu = s * (1.f / 128.f);
        float var = ss * (1.f / 128.f) - mu * mu;
        float rs = rsqrtf(var + 1e-5f);
        float l[8];
#pragma unroll
        for (int jj = 0; jj < 4; ++jj) {
            l[2 * jj]     = (o[2 * jj] - mu) * rs * gg[jj].x + bt[jj].x;
            l[2 * jj + 1] = (o[2 * jj + 1] - mu) * rs * gg[jj].y + bt[jj].y;
        }
        if (MODE == 0) {
#pragma unroll
            for (int j = 0; j < 8; ++j) l[j] = fmaxf(l[j], 0.f);
            if (ok) {
                __half2* hrow = (__half2*)h16 + gm * 64;
#pragma unroll
                for (int jj = 0; jj < 4; ++jj)
                    hrow[tx + 16 * jj] = __floats2half2_rn(l[2 * jj], l[2 * jj + 1]);
            }
        } else {
            if (ok) {
#pragma unroll
                for (int jj = 0; jj < 4; ++jj)
                    *(float2*)(out + gm * 128 + tx * 2 + 32 * jj) =
                        make_float2(l[2 * jj], l[2 * jj + 1]);
            }
        }
    }
}

// ------------------------- Launch -------------------------

extern "C" void kernel_launch(void* const* d_in, const int* in_sizes, int n_in,
                              void* d_out, int out_size, void* d_ws, size_t ws_size,
                              hipStream_t stream) {
    const int*   x    = (const int*)d_in[0];
    const int*   ei   = (const int*)d_in[1];
    const int*   attr = (const int*)d_in[2];
    const float* aemb = (const float*)d_in[3];
    const float* bemb = (const float*)d_in[4];
    const float* Wf   = (const float*)d_in[5];
    const float* bf   = (const float*)d_in[6];
    const float* gam  = (const float*)d_in[7];
    const float* bet  = (const float*)d_in[8];
    float* out = (float*)d_out;

    const int N = in_sizes[0] / NA;        // 50000
    const int E = in_sizes[1] / 2;         // 625000
    const int L = in_sizes[5] / (D * D);   // 7

    char* ws = (char*)d_ws;
    size_t o = 0;
    auto carve = [&](size_t bytes) -> void* {
        void* p = (void*)(ws + o);
        o += (bytes + 255) & ~(size_t)255;
        return p;
    };
    float*  h      = (float*)carve((size_t)N * D * 4);   // fp32 residual chain
    __half* h16    = (__half*)carve((size_t)N * D * 2);  // fp16 gather table
    float*  t      = (float*)carve((size_t)N * D * 4);
    int2*   recs   = (int2*)carve((size_t)E * 8);
    __half* comb16 = (__half*)carve(512 * D * 2);
    int*    deg    = (int*)carve((size_t)N * 4);
    int*    cur    = (int*)carve((size_t)N * 4);
    int*    offs   = (int*)carve((size_t)(N + 1) * 4);
    int*    bsum   = (int*)carve(4096);
    int*    bexc   = (int*)carve(4096);

    const int* src = ei;
    const int* dst = ei + E;

    hipMemsetAsync(deg, 0, (size_t)N * 4, stream);
    hipMemsetAsync(cur, 0, (size_t)N * 4, stream);

    int ebl = (E + 255) / 256;
    int nbl = (N + 255) / 256;  // 196 (<=256 required by k_scan_b)
    k_comb<<<64, 256, 0, stream>>>(bemb, comb16);
    k_hist<<<ebl, 256, 0, stream>>>(dst, deg, E);
    k_scan_a<<<nbl, 256, 0, stream>>>(deg, offs, bsum, N);
    k_scan_b<<<1, 256, 0, stream>>>(bsum, bexc, nbl);
    k_scan_c<<<nbl, 256, 0, stream>>>(offs, bexc, N);
    k_fill<<<ebl, 256, 0, stream>>>(src, dst, attr, offs, cur, recs, E);

    int wbl = (N * 64 + 255) / 256;  // wave per node
    k_atom<<<wbl, 256, 0, stream>>>(x, aemb, h16, N);

    int gbl = (N + 127) / 128;  // 391 blocks
    for (int l = 0; l < L; ++l) {
        k_agg<<<wbl, 256, 0, stream>>>(h16, recs, offs, comb16, t, N);
        if (l == L - 1) {
            k_gemm<1><<<gbl, 256, 0, stream>>>(t, Wf + l * D * D, bf + l * D, h, h,
                                               gam + l * D, bet + l * D, h16, out,
                                               N, 1);
        } else {
            k_gemm<0><<<gbl, 256, 0, stream>>>(t, Wf + l * D * D, bf + l * D, h, h,
                                               gam + l * D, bet + l * D, h16, out,
                                               N, l > 0 ? 1 : 0);
        }
    }
}

// Round 6
// 673.296 us; speedup vs baseline: 1.1618x; 1.0340x over previous
//
#include <hip/hip_runtime.h>
#include <hip/hip_fp16.h>
#include <math.h>

// DeeperGCN on MI355X. N=50000, E=625000, D=128, L=7.
// All inter-kernel [N,128] streams are fp16 (gather table h16, aggregation
// output t16, residual chain hres16) — each is LN-renormalized downstream so
// fp16 rounding stays ~1e-3 relative. CSR-by-dst build; direct-exp softmax
// aggregation (logits structurally bounded -> no running max); fp32 VALU GEMM
// (128x128 tile, 8x8 micro, transposed-A LDS) with fused bias/res/LN(+ReLU)
// epilogue emitting both the fp16 residual and the next gather table.

constexpr int D = 128;
constexpr int NA = 9;   // atom feats
constexpr int NB = 3;   // bond feats

// ------------------------- CSR build -------------------------

__global__ void k_hist(const int* __restrict__ dst, int* __restrict__ deg, int E) {
    int e = blockIdx.x * 256 + threadIdx.x;
    if (e < E) atomicAdd(&deg[dst[e]], 1);
}

__global__ void k_scan_a(const int* __restrict__ deg, int* __restrict__ offs,
                         int* __restrict__ bsum, int N) {
    __shared__ int s[256];
    int i = blockIdx.x * 256 + threadIdx.x;
    int v = (i < N) ? deg[i] : 0;
    s[threadIdx.x] = v;
    __syncthreads();
    for (int d = 1; d < 256; d <<= 1) {
        int add = (threadIdx.x >= d) ? s[threadIdx.x - d] : 0;
        __syncthreads();
        s[threadIdx.x] += add;
        __syncthreads();
    }
    if (i < N) offs[i + 1] = s[threadIdx.x];
    if (threadIdx.x == 255) bsum[blockIdx.x] = s[255];
    if (i == 0) offs[0] = 0;
}

// nb must be <= 256 (N=50000 -> nb=196)
__global__ void k_scan_b(const int* __restrict__ bsum, int* __restrict__ bexc, int nb) {
    __shared__ int s[256];
    int t = threadIdx.x;
    int v = (t < nb) ? bsum[t] : 0;
    s[t] = v;
    __syncthreads();
    for (int d = 1; d < 256; d <<= 1) {
        int add = (t >= d) ? s[t - d] : 0;
        __syncthreads();
        s[t] += add;
        __syncthreads();
    }
    if (t < nb) bexc[t] = s[t] - v;  // exclusive block prefix
}

__global__ void k_scan_c(int* __restrict__ offs, const int* __restrict__ bexc, int N) {
    int i = blockIdx.x * 256 + threadIdx.x;
    if (i < N) offs[i + 1] += bexc[blockIdx.x];
}

__global__ void k_fill(const int* __restrict__ src, const int* __restrict__ dst,
                       const int* __restrict__ attr, const int* __restrict__ offs,
                       int* __restrict__ cur, int2* __restrict__ recs, int E) {
    int e = blockIdx.x * 256 + threadIdx.x;
    if (e >= E) return;
    int d = dst[e];
    int pos = offs[d] + atomicAdd(&cur[d], 1);
    int cidx = attr[e * 3] * 64 + attr[e * 3 + 1] * 8 + attr[e * 3 + 2];
    recs[pos] = make_int2(src[e], cidx);
}

// comb16[c][d] = fp16(b0[c>>6][d] + b1[(c>>3)&7][d] + b2[c&7][d])   (512 x 128)
__global__ void k_comb(const float* __restrict__ bemb, __half* __restrict__ comb16) {
    int gid = blockIdx.x * 256 + threadIdx.x;  // 512*32 float4s
    int c = gid >> 5, q = gid & 31;
    int a0 = c >> 6, a1 = (c >> 3) & 7, a2 = c & 7;
    float4 v0 = *(const float4*)(bemb + (a0)*D + q * 4);
    float4 v1 = *(const float4*)(bemb + (8 + a1) * D + q * 4);
    float4 v2 = *(const float4*)(bemb + (16 + a2) * D + q * 4);
    __half2* c2 = (__half2*)comb16;
    c2[c * 64 + q * 2]     = __floats2half2_rn(v0.x + v1.x + v2.x, v0.y + v1.y + v2.y);
    c2[c * 64 + q * 2 + 1] = __floats2half2_rn(v0.z + v1.z + v2.z, v0.w + v1.w + v2.w);
}

// ------------------------- Atom encoder -------------------------
// wave per node; lane holds d = 2*lane, 2*lane+1. Emits fp16 gather table.

__global__ void k_atom(const int* __restrict__ x, const float* __restrict__ aemb,
                       __half* __restrict__ h16, int N) {
    int wid = (blockIdx.x * blockDim.x + threadIdx.x) >> 6;
    int lane = threadIdx.x & 63;
    if (wid >= N) return;
    const int* xr = x + wid * NA;
    float ax = 0.f, ay = 0.f;
#pragma unroll
    for (int f = 0; f < NA; ++f) {
        int v = xr[f];  // wave-uniform broadcast
        const float2 e = *(const float2*)(aemb + (f * 64 + v) * D + 2 * lane);
        ax += e.x; ay += e.y;
    }
    ((__half2*)h16)[wid * 64 + lane] = __floats2half2_rn(ax, ay);
}

// ------------------------- Aggregation (direct-exp softmax, fp16 all) ------
// wave per node; t16[n] = h16[n] + m[n]. Logits bounded (<~13) so exp2 never
// overflows -> no running max. Edge metadata scalarized; A/B double-group
// pipeline (4 edges/group), -inf-masked dummy slots.

__global__ __launch_bounds__(256) void k_agg(const __half* __restrict__ h16,
                      const int2* __restrict__ recs,
                      const int* __restrict__ offs, const __half* __restrict__ comb16,
                      __half* __restrict__ t16, int N) {
    int wid = (blockIdx.x * blockDim.x + threadIdx.x) >> 6;
    int lane = threadIdx.x & 63;
    if (wid >= N) return;
    int su = __builtin_amdgcn_readfirstlane(offs[wid]);
    int eu = __builtin_amdgcn_readfirstlane(offs[wid + 1]);
    __half2 hm2 = ((const __half2*)h16)[wid * 64 + lane];
    float2 hme = make_float2(__low2float(hm2), __high2float(hm2));
    if (su >= eu) {  // empty segment: m = 0
        ((__half2*)t16)[wid * 64 + lane] = hm2;
        return;
    }
    constexpr float L2E = 1.4426950408889634f;
    float Sx = 0.f, Sy = 0.f, Wx = 0.f, Wy = 0.f;
    int last = eu - 1;

    const __half2* hrow = (const __half2*)h16 + lane;    // row r at hrow[r*64]
    const __half2* crow = (const __half2*)comb16 + lane;

    __half2 ha[4], ca[4], hb[4], cb[4];

    auto loadg = [&](int gb, __half2* hs, __half2* cs) {
#pragma unroll
        for (int i = 0; i < 4; ++i) {
            int idx = gb + i; idx = (idx < last) ? idx : last;
            int2 rr = recs[idx];
            int sj = __builtin_amdgcn_readfirstlane(rr.x);
            int cj = __builtin_amdgcn_readfirstlane(rr.y);
            hs[i] = hrow[sj * 64];
            cs[i] = crow[cj * 64];
        }
    };
    auto compg = [&](int gb, const __half2* hs, const __half2* cs) {
        float px[4], py[4], vx[4], vy[4];
#pragma unroll
        for (int i = 0; i < 4; ++i) {
            float hx = __low2float(hs[i]), hy = __high2float(hs[i]);
            float cx = __low2float(cs[i]), cy = __high2float(cs[i]);
            vx[i] = fmaxf(hx + cx, 0.f) + 1e-7f;
            vy[i] = fmaxf(hy + cy, 0.f) + 1e-7f;
            bool valid = (gb + i) < eu;  // wave-uniform
            float uxv = valid ? vx[i] * L2E : -INFINITY;
            float uyv = valid ? vy[i] * L2E : -INFINITY;
            px[i] = __builtin_amdgcn_exp2f(uxv);
            py[i] = __builtin_amdgcn_exp2f(uyv);
        }
        Sx += (px[0] + px[1]) + (px[2] + px[3]);
        Sy += (py[0] + py[1]) + (py[2] + py[3]);
        Wx += fmaf(px[0], vx[0], px[1] * vx[1]) + fmaf(px[2], vx[2], px[3] * vx[3]);
        Wy += fmaf(py[0], vy[0], py[1] * vy[1]) + fmaf(py[2], vy[2], py[3] * vy[3]);
    };

    loadg(su, ha, ca);
    loadg(su + 4, hb, cb);
    for (int e = su; e < eu; e += 8) {
        compg(e, ha, ca);
        loadg(e + 8, ha, ca);      // prefetch for next iteration's A
        compg(e + 4, hb, cb);
        loadg(e + 12, hb, cb);     // prefetch for next iteration's B
    }
    float mx = Wx / (Sx + 1e-16f);
    float my = Wy / (Sy + 1e-16f);
    ((__half2*)t16)[wid * 64 + lane] = __floats2half2_rn(hme.x + mx, hme.y + my);
}

// ------------------------- GEMM + fused LN(+ReLU) -------------------------
// hnew = t16 @ W + b (+ hres16). MODE 0: write hres16 (fp16 residual) and
// h16 = fp16(relu(LN(hnew))). MODE 1 (last layer): write out = LN(hnew) fp32.
// 128x128 tile, 256 threads, 8x8 micro-tile. A staged transposed As[k][m]
// (stride 132, fp16->fp32 converted at staging); B read as b64 pairs at
// j = tx*2 + 32*jj.

template <int MODE>
__global__ __launch_bounds__(256) void k_gemm(const __half* __restrict__ A16,
                                              const float* __restrict__ Wl,
                                              const float* __restrict__ bl,
                                              const __half* __restrict__ res16,
                                              __half* __restrict__ hres16,
                                              const float* __restrict__ g,
                                              const float* __restrict__ bta,
                                              __half* __restrict__ h16,
                                              float* __restrict__ out,
                                              int N, int useRes) {
    __shared__ float As[32 * 132];  // [k][m], m-contiguous, stride 132
    __shared__ float Bs[32 * 128];  // [k][j]
    int tid = threadIdx.x;
    int tx = tid & 15;   // j lanes: j = tx*2 + 32*jj + s
    int ty = tid >> 4;   // m rows: ty*8 + i, i=0..7
    int m0 = blockIdx.x * 128;

    float acc[8][8];
#pragma unroll
    for (int i = 0; i < 8; ++i)
#pragma unroll
        for (int j = 0; j < 8; ++j) acc[i][j] = 0.f;

    for (int kk0 = 0; kk0 < 128; kk0 += 32) {
#pragma unroll
        for (int it = 0; it < 2; ++it) {  // stage A chunk 128x32 fp16, transposed
            int lin = it * 256 + tid;      // 0..511
            int node = lin >> 2, kq = lin & 3;  // 8 halves per slot
            int gm = m0 + node;
            float4 raw = make_float4(0.f, 0.f, 0.f, 0.f);
            if (gm < N) raw = *(const float4*)(A16 + gm * 128 + kk0 + kq * 8);
            const __half2* hp = (const __half2*)&raw;
#pragma unroll
            for (int j = 0; j < 4; ++j) {
                float2 f = make_float2(__low2float(hp[j]), __high2float(hp[j]));
                As[(kq * 8 + 2 * j) * 132 + node]     = f.x;
                As[(kq * 8 + 2 * j + 1) * 132 + node] = f.y;
            }
        }
#pragma unroll
        for (int it = 0; it < 4; ++it) {  // stage B chunk 32x128
            int lin = it * 256 + tid;
            int k = lin >> 5, jq = lin & 31;
            *(float4*)(Bs + k * 128 + jq * 4) = *(const float4*)(Wl + (kk0 + k) * 128 + jq * 4);
        }
        __syncthreads();
#pragma unroll
        for (int kk = 0; kk < 32; ++kk) {
            float4 a_lo = *(const float4*)(As + kk * 132 + ty * 8);
            float4 a_hi = *(const float4*)(As + kk * 132 + ty * 8 + 4);
            float2 bv[4];
#pragma unroll
            for (int jj = 0; jj < 4; ++jj)
                bv[jj] = *(const float2*)(Bs + kk * 128 + tx * 2 + 32 * jj);
            float am[8] = {a_lo.x, a_lo.y, a_lo.z, a_lo.w,
                           a_hi.x, a_hi.y, a_hi.z, a_hi.w};
#pragma unroll
            for (int i = 0; i < 8; ++i)
#pragma unroll
                for (int jj = 0; jj < 4; ++jj) {
                    acc[i][2 * jj]     = fmaf(am[i], bv[jj].x, acc[i][2 * jj]);
                    acc[i][2 * jj + 1] = fmaf(am[i], bv[jj].y, acc[i][2 * jj + 1]);
                }
        }
        __syncthreads();
    }

    // epilogue: j(jj,s) = 32*jj + tx*2 + s
    float2 bb[4], gg[4], bt[4];
#pragma unroll
    for (int jj = 0; jj < 4; ++jj) {
        bb[jj] = *(const float2*)(bl + tx * 2 + 32 * jj);
        gg[jj] = *(const float2*)(g + tx * 2 + 32 * jj);
        bt[jj] = *(const float2*)(bta + tx * 2 + 32 * jj);
    }
#pragma unroll
    for (int i = 0; i < 8; ++i) {
        int gm = m0 + ty * 8 + i;
        bool ok = gm < N;
        float o[8];
#pragma unroll
        for (int jj = 0; jj < 4; ++jj) {
            o[2 * jj]     = acc[i][2 * jj] + bb[jj].x;
            o[2 * jj + 1] = acc[i][2 * jj + 1] + bb[jj].y;
        }
        if (useRes && ok) {
#pragma unroll
            for (int jj = 0; jj < 4; ++jj) {
                __half2 rr = *(const __half2*)(res16 + gm * 128 + tx * 2 + 32 * jj);
                o[2 * jj]     += __low2float(rr);
                o[2 * jj + 1] += __high2float(rr);
            }
        }
        if (MODE == 0 && ok) {
#pragma unroll
            for (int jj = 0; jj < 4; ++jj)
                *(__half2*)(hres16 + gm * 128 + tx * 2 + 32 * jj) =
                    __floats2half2_rn(o[2 * jj], o[2 * jj + 1]);
        }
        // LN across the 16-lane tx group (same wave)
        float s = 0.f, ss = 0.f;
#pragma unroll
        for (int j = 0; j < 8; ++j) { s += o[j]; ss += o[j] * o[j]; }
#pragma unroll
        for (int off = 1; off < 16; off <<= 1) {
            s += __shfl_xor(s, off, 64);
            ss += __shfl_xor(ss, off, 64);
        }
        float mu = s * (1.f / 128.f);
        float var = ss * (1.f / 128.f) - mu * mu;
        float rs = rsqrtf(var + 1e-5f);
        float l[8];
#pragma unroll
        for (int jj = 0; jj < 4; ++jj) {
            l[2 * jj]     = (o[2 * jj] - mu) * rs * gg[jj].x + bt[jj].x;
            l[2 * jj + 1] = (o[2 * jj + 1] - mu) * rs * gg[jj].y + bt[jj].y;
        }
        if (MODE == 0) {
#pragma unroll
            for (int j = 0; j < 8; ++j) l[j] = fmaxf(l[j], 0.f);
            if (ok) {
                __half2* hrow = (__half2*)h16 + gm * 64;
#pragma unroll
                for (int jj = 0; jj < 4; ++jj)
                    hrow[tx + 16 * jj] = __floats2half2_rn(l[2 * jj], l[2 * jj + 1]);
            }
        } else {
            if (ok) {
#pragma unroll
                for (int jj = 0; jj < 4; ++jj)
                    *(float2*)(out + gm * 128 + tx * 2 + 32 * jj) =
                        make_float2(l[2 * jj], l[2 * jj + 1]);
            }
        }
    }
}

// ------------------------- Launch -------------------------

extern "C" void kernel_launch(void* const* d_in, const int* in_sizes, int n_in,
                              void* d_out, int out_size, void* d_ws, size_t ws_size,
                              hipStream_t stream) {
    const int*   x    = (const int*)d_in[0];
    const int*   ei   = (const int*)d_in[1];
    const int*   attr = (const int*)d_in[2];
    const float* aemb = (const float*)d_in[3];
    const float* bemb = (const float*)d_in[4];
    const float* Wf   = (const float*)d_in[5];
    const float* bf   = (const float*)d_in[6];
    const float* gam  = (const float*)d_in[7];
    const float* bet  = (const float*)d_in[8];
    float* out = (float*)d_out;

    const int N = in_sizes[0] / NA;        // 50000
    const int E = in_sizes[1] / 2;         // 625000
    const int L = in_sizes[5] / (D * D);   // 7

    char* ws = (char*)d_ws;
    size_t o = 0;
    auto carve = [&](size_t bytes) -> void* {
        void* p = (void*)(ws + o);
        o += (bytes + 255) & ~(size_t)255;
        return p;
    };
    __half* hres16 = (__half*)carve((size_t)N * D * 2);  // fp16 residual chain
    __half* h16    = (__half*)carve((size_t)N * D * 2);  // fp16 gather table
    __half* t16    = (__half*)carve((size_t)N * D * 2);  // fp16 agg output
    int2*   recs   = (int2*)carve((size_t)E * 8);
    __half* comb16 = (__half*)carve(512 * D * 2);
    int*    deg    = (int*)carve((size_t)N * 4);
    int*    cur    = (int*)carve((size_t)N * 4);
    int*    offs   = (int*)carve((size_t)(N + 1) * 4);
    int*    bsum   = (int*)carve(4096);
    int*    bexc   = (int*)carve(4096);

    const int* src = ei;
    const int* dst = ei + E;

    hipMemsetAsync(deg, 0, (size_t)N * 4, stream);
    hipMemsetAsync(cur, 0, (size_t)N * 4, stream);

    int ebl = (E + 255) / 256;
    int nbl = (N + 255) / 256;  // 196 (<=256 required by k_scan_b)
    k_comb<<<64, 256, 0, stream>>>(bemb, comb16);
    k_hist<<<ebl, 256, 0, stream>>>(dst, deg, E);
    k_scan_a<<<nbl, 256, 0, stream>>>(deg, offs, bsum, N);
    k_scan_b<<<1, 256, 0, stream>>>(bsum, bexc, nbl);
    k_scan_c<<<nbl, 256, 0, stream>>>(offs, bexc, N);
    k_fill<<<ebl, 256, 0, stream>>>(src, dst, attr, offs, cur, recs, E);

    int wbl = (N * 64 + 255) / 256;  // wave per node
    k_atom<<<wbl, 256, 0, stream>>>(x, aemb, h16, N);

    int gbl = (N + 127) / 128;  // 391 blocks
    for (int l = 0; l < L; ++l) {
        k_agg<<<wbl, 256, 0, stream>>>(h16, recs, offs, comb16, t16, N);
        if (l == L - 1) {
            k_gemm<1><<<gbl, 256, 0, stream>>>(t16, Wf + l * D * D, bf + l * D,
                                               hres16, hres16,
                                               gam + l * D, bet + l * D, h16, out,
                                               N, 1);
        } else {
            k_gemm<0><<<gbl, 256, 0, stream>>>(t16, Wf + l * D * D, bf + l * D,
                                               hres16, hres16,
                                               gam + l * D, bet + l * D, h16, out,
                                               N, l > 0 ? 1 : 0);
        }
    }
}

// Round 7
// 667.394 us; speedup vs baseline: 1.1720x; 1.0088x over previous
//
#include <hip/hip_runtime.h>
#include <hip/hip_fp16.h>
#include <math.h>

// DeeperGCN on MI355X. N=50000, E=625000, D=128, L=7.
// fp16 inter-kernel streams; CSR-by-dst build; direct-exp softmax aggregation
// (wave/node, scalarized edge metadata, A/B pipelined groups); GEMM via
// v_mfma_f32_16x16x32_f16 computing the TRANSPOSED product D[f][node] so the
// MFMA C-layout puts one node per lane-column -> 2-shuffle LayerNorm and
// vectorized stores. Zero LDS in the GEMM (Wt16 is L1-hot broadcast).

constexpr int D = 128;
constexpr int NA = 9;   // atom feats
constexpr int NB = 3;   // bond feats

using half8  = __attribute__((ext_vector_type(8))) _Float16;
using floatx4 = __attribute__((ext_vector_type(4))) float;

// ------------------------- CSR build -------------------------

__global__ void k_hist(const int* __restrict__ dst, int* __restrict__ deg, int E) {
    int e = blockIdx.x * 256 + threadIdx.x;
    if (e < E) atomicAdd(&deg[dst[e]], 1);
}

__global__ void k_scan_a(const int* __restrict__ deg, int* __restrict__ offs,
                         int* __restrict__ bsum, int N) {
    __shared__ int s[256];
    int i = blockIdx.x * 256 + threadIdx.x;
    int v = (i < N) ? deg[i] : 0;
    s[threadIdx.x] = v;
    __syncthreads();
    for (int d = 1; d < 256; d <<= 1) {
        int add = (threadIdx.x >= d) ? s[threadIdx.x - d] : 0;
        __syncthreads();
        s[threadIdx.x] += add;
        __syncthreads();
    }
    if (i < N) offs[i + 1] = s[threadIdx.x];
    if (threadIdx.x == 255) bsum[blockIdx.x] = s[255];
    if (i == 0) offs[0] = 0;
}

// nb must be <= 256 (N=50000 -> nb=196)
__global__ void k_scan_b(const int* __restrict__ bsum, int* __restrict__ bexc, int nb) {
    __shared__ int s[256];
    int t = threadIdx.x;
    int v = (t < nb) ? bsum[t] : 0;
    s[t] = v;
    __syncthreads();
    for (int d = 1; d < 256; d <<= 1) {
        int add = (t >= d) ? s[t - d] : 0;
        __syncthreads();
        s[t] += add;
        __syncthreads();
    }
    if (t < nb) bexc[t] = s[t] - v;  // exclusive block prefix
}

__global__ void k_scan_c(int* __restrict__ offs, const int* __restrict__ bexc, int N) {
    int i = blockIdx.x * 256 + threadIdx.x;
    if (i < N) offs[i + 1] += bexc[blockIdx.x];
}

__global__ void k_fill(const int* __restrict__ src, const int* __restrict__ dst,
                       const int* __restrict__ attr, const int* __restrict__ offs,
                       int* __restrict__ cur, int2* __restrict__ recs, int E) {
    int e = blockIdx.x * 256 + threadIdx.x;
    if (e >= E) return;
    int d = dst[e];
    int pos = offs[d] + atomicAdd(&cur[d], 1);
    int cidx = attr[e * 3] * 64 + attr[e * 3 + 1] * 8 + attr[e * 3 + 2];
    recs[pos] = make_int2(src[e], cidx);
}

// comb16[c][d] = fp16(b0[c>>6][d] + b1[(c>>3)&7][d] + b2[c&7][d])   (512 x 128)
__global__ void k_comb(const float* __restrict__ bemb, __half* __restrict__ comb16) {
    int gid = blockIdx.x * 256 + threadIdx.x;  // 512*32 float4s
    int c = gid >> 5, q = gid & 31;
    int a0 = c >> 6, a1 = (c >> 3) & 7, a2 = c & 7;
    float4 v0 = *(const float4*)(bemb + (a0)*D + q * 4);
    float4 v1 = *(const float4*)(bemb + (8 + a1) * D + q * 4);
    float4 v2 = *(const float4*)(bemb + (16 + a2) * D + q * 4);
    __half2* c2 = (__half2*)comb16;
    c2[c * 64 + q * 2]     = __floats2half2_rn(v0.x + v1.x + v2.x, v0.y + v1.y + v2.y);
    c2[c * 64 + q * 2 + 1] = __floats2half2_rn(v0.z + v1.z + v2.z, v0.w + v1.w + v2.w);
}

// Wt16[l][f][k] = fp16(W[l][k][f])  -- K-major transposed fp16 weights
__global__ void k_wt(const float* __restrict__ W, __half* __restrict__ Wt16, int total) {
    int o = blockIdx.x * 256 + threadIdx.x;
    if (o >= total) return;
    int l = o >> 14;          // /(128*128)
    int rem = o & 16383;
    int f = rem >> 7, k = rem & 127;
    Wt16[o] = __float2half_rn(W[(l << 14) + k * 128 + f]);
}

// ------------------------- Atom encoder -------------------------
// wave per node; lane holds d = 2*lane, 2*lane+1. Emits fp16 gather table.

__global__ void k_atom(const int* __restrict__ x, const float* __restrict__ aemb,
                       __half* __restrict__ h16, int N) {
    int wid = (blockIdx.x * blockDim.x + threadIdx.x) >> 6;
    int lane = threadIdx.x & 63;
    if (wid >= N) return;
    const int* xr = x + wid * NA;
    float ax = 0.f, ay = 0.f;
#pragma unroll
    for (int f = 0; f < NA; ++f) {
        int v = xr[f];  // wave-uniform broadcast
        const float2 e = *(const float2*)(aemb + (f * 64 + v) * D + 2 * lane);
        ax += e.x; ay += e.y;
    }
    ((__half2*)h16)[wid * 64 + lane] = __floats2half2_rn(ax, ay);
}

// ------------------------- Aggregation (direct-exp softmax, fp16 all) ------
// wave per node; t16[n] = h16[n] + m[n]. Logits bounded (<~13) so exp2 never
// overflows -> no running max. Edge metadata scalarized; A/B double-group
// pipeline (4 edges/group), -inf-masked dummy slots.

__global__ __launch_bounds__(256) void k_agg(const __half* __restrict__ h16,
                      const int2* __restrict__ recs,
                      const int* __restrict__ offs, const __half* __restrict__ comb16,
                      __half* __restrict__ t16, int N) {
    int wid = (blockIdx.x * blockDim.x + threadIdx.x) >> 6;
    int lane = threadIdx.x & 63;
    if (wid >= N) return;
    int su = __builtin_amdgcn_readfirstlane(offs[wid]);
    int eu = __builtin_amdgcn_readfirstlane(offs[wid + 1]);
    __half2 hm2 = ((const __half2*)h16)[wid * 64 + lane];
    float2 hme = make_float2(__low2float(hm2), __high2float(hm2));
    if (su >= eu) {  // empty segment: m = 0
        ((__half2*)t16)[wid * 64 + lane] = hm2;
        return;
    }
    constexpr float L2E = 1.4426950408889634f;
    float Sx = 0.f, Sy = 0.f, Wx = 0.f, Wy = 0.f;
    int last = eu - 1;

    const __half2* hrow = (const __half2*)h16 + lane;    // row r at hrow[r*64]
    const __half2* crow = (const __half2*)comb16 + lane;

    __half2 ha[4], ca[4], hb[4], cb[4];

    auto loadg = [&](int gb, __half2* hs, __half2* cs) {
#pragma unroll
        for (int i = 0; i < 4; ++i) {
            int idx = gb + i; idx = (idx < last) ? idx : last;
            int2 rr = recs[idx];
            int sj = __builtin_amdgcn_readfirstlane(rr.x);
            int cj = __builtin_amdgcn_readfirstlane(rr.y);
            hs[i] = hrow[sj * 64];
            cs[i] = crow[cj * 64];
        }
    };
    auto compg = [&](int gb, const __half2* hs, const __half2* cs) {
        float px[4], py[4], vx[4], vy[4];
#pragma unroll
        for (int i = 0; i < 4; ++i) {
            float hx = __low2float(hs[i]), hy = __high2float(hs[i]);
            float cx = __low2float(cs[i]), cy = __high2float(cs[i]);
            vx[i] = fmaxf(hx + cx, 0.f) + 1e-7f;
            vy[i] = fmaxf(hy + cy, 0.f) + 1e-7f;
            bool valid = (gb + i) < eu;  // wave-uniform
            float uxv = valid ? vx[i] * L2E : -INFINITY;
            float uyv = valid ? vy[i] * L2E : -INFINITY;
            px[i] = __builtin_amdgcn_exp2f(uxv);
            py[i] = __builtin_amdgcn_exp2f(uyv);
        }
        Sx += (px[0] + px[1]) + (px[2] + px[3]);
        Sy += (py[0] + py[1]) + (py[2] + py[3]);
        Wx += fmaf(px[0], vx[0], px[1] * vx[1]) + fmaf(px[2], vx[2], px[3] * vx[3]);
        Wy += fmaf(py[0], vy[0], py[1] * vy[1]) + fmaf(py[2], vy[2], py[3] * vy[3]);
    };

    loadg(su, ha, ca);
    loadg(su + 4, hb, cb);
    for (int e = su; e < eu; e += 8) {
        compg(e, ha, ca);
        loadg(e + 8, ha, ca);      // prefetch for next iteration's A
        compg(e + 4, hb, cb);
        loadg(e + 12, hb, cb);     // prefetch for next iteration's B
    }
    float mx = Wx / (Sx + 1e-16f);
    float my = Wy / (Sy + 1e-16f);
    ((__half2*)t16)[wid * 64 + lane] = __floats2half2_rn(hme.x + mx, hme.y + my);
}

// ------------------------- MFMA GEMM + fused LN(+ReLU) ---------------------
// Computes D[f][node] = sum_k Wt16[f][k] * A16[node][k]  (transposed product)
// with v_mfma_f32_16x16x32_f16. C/D layout: col(lane&15)=node,
// row(quad*4+reg)=f -> each lane holds features of ONE node; LN reduction is
// per-lane sum + shfl_xor(16) + shfl_xor(32). No LDS, no barriers.
// Wave covers 128 features x 16 nodes; block (4 waves) covers 64 nodes.
// MODE 0: write hres16 = o (fp16) and h16 = fp16(relu(LN(o))).
// MODE 1: write out = LN(o) fp32.

template <int MODE>
__global__ __launch_bounds__(256) void k_gemm(const __half* __restrict__ A16,
                                              const __half* __restrict__ Wt16,
                                              const float* __restrict__ bl,
                                              const __half* __restrict__ res16,
                                              __half* __restrict__ hres16,
                                              const float* __restrict__ g,
                                              const float* __restrict__ bta,
                                              __half* __restrict__ h16,
                                              float* __restrict__ out,
                                              int N, int useRes) {
    int lane = threadIdx.x & 63;
    int wave = threadIdx.x >> 6;
    int quad = lane >> 4, col = lane & 15;
    int node = blockIdx.x * 64 + wave * 16 + col;
    bool nok = node < N;
    int nc = nok ? node : N - 1;  // clamp (row N-1 is valid data)

    // B-operand: this node's fp16 row, 8 contiguous halves per k-step
    const __half* arow = A16 + (size_t)nc * 128;
    half8 bfrag[4];
#pragma unroll
    for (int ks = 0; ks < 4; ++ks)
        bfrag[ks] = *(const half8*)(arow + ks * 32 + quad * 8);

    floatx4 acc[8];
#pragma unroll
    for (int ft = 0; ft < 8; ++ft) acc[ft] = (floatx4){0.f, 0.f, 0.f, 0.f};

#pragma unroll
    for (int ft = 0; ft < 8; ++ft) {
        const __half* wrow = Wt16 + (size_t)(ft * 16 + col) * 128;  // A-op: m=f
#pragma unroll
        for (int ks = 0; ks < 4; ++ks) {
            half8 afrag = *(const half8*)(wrow + ks * 32 + quad * 8);
            acc[ft] = __builtin_amdgcn_mfma_f32_16x16x32_f16(afrag, bfrag[ks],
                                                             acc[ft], 0, 0, 0);
        }
    }

    // o = acc + b (+ res); accumulate LN sums; store fp16 residual (MODE 0)
    float s = 0.f, ss = 0.f;
#pragma unroll
    for (int ft = 0; ft < 8; ++ft) {
        int f0 = ft * 16 + quad * 4;  // 4 consecutive features per lane
        float4 bb = *(const float4*)(bl + f0);
        float o0 = acc[ft][0] + bb.x, o1 = acc[ft][1] + bb.y;
        float o2 = acc[ft][2] + bb.z, o3 = acc[ft][3] + bb.w;
        if (useRes) {
            uint2 rr = *(const uint2*)(res16 + (size_t)nc * 128 + f0);
            __half2 r01 = *(__half2*)&rr.x, r23 = *(__half2*)&rr.y;
            o0 += __low2float(r01); o1 += __high2float(r01);
            o2 += __low2float(r23); o3 += __high2float(r23);
        }
        acc[ft][0] = o0; acc[ft][1] = o1; acc[ft][2] = o2; acc[ft][3] = o3;
        s += (o0 + o1) + (o2 + o3);
        ss += fmaf(o0, o0, o1 * o1) + fmaf(o2, o2, o3 * o3);
        if (MODE == 0 && nok) {
            __half2 h01 = __floats2half2_rn(o0, o1);
            __half2 h23 = __floats2half2_rn(o2, o3);
            uint2 pk = make_uint2(*(unsigned*)&h01, *(unsigned*)&h23);
            *(uint2*)(hres16 + (size_t)node * 128 + f0) = pk;
        }
    }
    // LN over the node's 128 features: 4 quads hold disjoint feature sets
    s += __shfl_xor(s, 16, 64);  ss += __shfl_xor(ss, 16, 64);
    s += __shfl_xor(s, 32, 64);  ss += __shfl_xor(ss, 32, 64);
    float mu = s * (1.f / 128.f);
    float var = ss * (1.f / 128.f) - mu * mu;
    float rs = rsqrtf(var + 1e-5f);

#pragma unroll
    for (int ft = 0; ft < 8; ++ft) {
        int f0 = ft * 16 + quad * 4;
        float4 gg = *(const float4*)(g + f0);
        float4 bt = *(const float4*)(bta + f0);
        float l0 = (acc[ft][0] - mu) * rs * gg.x + bt.x;
        float l1 = (acc[ft][1] - mu) * rs * gg.y + bt.y;
        float l2 = (acc[ft][2] - mu) * rs * gg.z + bt.z;
        float l3 = (acc[ft][3] - mu) * rs * gg.w + bt.w;
        if (MODE == 0) {
            l0 = fmaxf(l0, 0.f); l1 = fmaxf(l1, 0.f);
            l2 = fmaxf(l2, 0.f); l3 = fmaxf(l3, 0.f);
            if (nok) {
                __half2 h01 = __floats2half2_rn(l0, l1);
                __half2 h23 = __floats2half2_rn(l2, l3);
                uint2 pk = make_uint2(*(unsigned*)&h01, *(unsigned*)&h23);
                *(uint2*)(h16 + (size_t)node * 128 + f0) = pk;
            }
        } else {
            if (nok)
                *(float4*)(out + (size_t)node * 128 + f0) =
                    make_float4(l0, l1, l2, l3);
        }
    }
}

// ------------------------- Launch -------------------------

extern "C" void kernel_launch(void* const* d_in, const int* in_sizes, int n_in,
                              void* d_out, int out_size, void* d_ws, size_t ws_size,
                              hipStream_t stream) {
    const int*   x    = (const int*)d_in[0];
    const int*   ei   = (const int*)d_in[1];
    const int*   attr = (const int*)d_in[2];
    const float* aemb = (const float*)d_in[3];
    const float* bemb = (const float*)d_in[4];
    const float* Wf   = (const float*)d_in[5];
    const float* bf   = (const float*)d_in[6];
    const float* gam  = (const float*)d_in[7];
    const float* bet  = (const float*)d_in[8];
    float* out = (float*)d_out;

    const int N = in_sizes[0] / NA;        // 50000
    const int E = in_sizes[1] / 2;         // 625000
    const int L = in_sizes[5] / (D * D);   // 7

    char* ws = (char*)d_ws;
    size_t o = 0;
    auto carve = [&](size_t bytes) -> void* {
        void* p = (void*)(ws + o);
        o += (bytes + 255) & ~(size_t)255;
        return p;
    };
    __half* hres16 = (__half*)carve((size_t)N * D * 2);  // fp16 residual chain
    __half* h16    = (__half*)carve((size_t)N * D * 2);  // fp16 gather table
    __half* t16    = (__half*)carve((size_t)N * D * 2);  // fp16 agg output
    int2*   recs   = (int2*)carve((size_t)E * 8);
    __half* comb16 = (__half*)carve(512 * D * 2);
    __half* Wt16   = (__half*)carve((size_t)L * D * D * 2);
    int*    deg    = (int*)carve((size_t)N * 4);
    int*    cur    = (int*)carve((size_t)N * 4);
    int*    offs   = (int*)carve((size_t)(N + 1) * 4);
    int*    bsum   = (int*)carve(4096);
    int*    bexc   = (int*)carve(4096);

    const int* src = ei;
    const int* dst = ei + E;

    hipMemsetAsync(deg, 0, (size_t)N * 4, stream);
    hipMemsetAsync(cur, 0, (size_t)N * 4, stream);

    int ebl = (E + 255) / 256;
    int nbl = (N + 255) / 256;  // 196 (<=256 required by k_scan_b)
    k_comb<<<64, 256, 0, stream>>>(bemb, comb16);
    int wtot = L * D * D;
    k_wt<<<(wtot + 255) / 256, 256, 0, stream>>>(Wf, Wt16, wtot);
    k_hist<<<ebl, 256, 0, stream>>>(dst, deg, E);
    k_scan_a<<<nbl, 256, 0, stream>>>(deg, offs, bsum, N);
    k_scan_b<<<1, 256, 0, stream>>>(bsum, bexc, nbl);
    k_scan_c<<<nbl, 256, 0, stream>>>(offs, bexc, N);
    k_fill<<<ebl, 256, 0, stream>>>(src, dst, attr, offs, cur, recs, E);

    int wbl = (N * 64 + 255) / 256;  // wave per node
    k_atom<<<wbl, 256, 0, stream>>>(x, aemb, h16, N);

    int gbl = (N + 63) / 64;  // 782 blocks, 64 nodes each
    for (int l = 0; l < L; ++l) {
        k_agg<<<wbl, 256, 0, stream>>>(h16, recs, offs, comb16, t16, N);
        if (l == L - 1) {
            k_gemm<1><<<gbl, 256, 0, stream>>>(t16, Wt16 + l * D * D, bf + l * D,
                                               hres16, hres16,
                                               gam + l * D, bet + l * D, h16, out,
                                               N, 1);
        } else {
            k_gemm<0><<<gbl, 256, 0, stream>>>(t16, Wt16 + l * D * D, bf + l * D,
                                               hres16, hres16,
                                               gam + l * D, bet + l * D, h16, out,
                                               N, l > 0 ? 1 : 0);
        }
    }
}